// Round 17
// baseline (56.631 us; speedup 1.0000x reference)
//
#include <hip/hip_runtime.h>

// DifferentiableCIndexLoss:
//   mask[i,j] = (t[i] < t[j]) && (e[i]==1)
//   loss = sum sigmoid((r[j]-r[i])/SIGMA) * mask ;  count = sum mask
//   out  = loss / (count + 1e-6)
//
// R17: sorted classification with the TWO fixes R16's decomposition demanded:
//  (1) prep = 2 nodes, NO memset (R16 prep ~17-19us was the whole loss):
//      k_hist (64blk: per-block LDS hist slices, pure overwrite) +
//      k_scatter (64blk: unroll-8 redundant column-sum of slices (MLP),
//      dual 256-thr scan, chunk/page bounds (block 0), E/F transform +
//      bucket scatter). Pattern passed correctness in R8/R9.
//  (2) balanced main: CHUNK=1024 (RPT=4) -> ~2048 tiles, grid 1024,
//      cg-MAJOR tile order: block's 2 strided tiles share rc, cg vs cg+128
//      -> classes anti-correlate (AT pairs with AF) -> no 1-tile/block
//      imbalance (R16's other failure).
// Classes by bucket bounds (strict inequalities => exact):
//   jpHi[cg] < rcLo[rc] -> all-false: skip before staging
//   jpLo[cg] > rcHi[rc] -> all-true: fma,fma,mul,rcp,add,fma per 2 pairs,
//                          no cmp/cndmask/count; count = nv*64 analytic;
//                          pads E=0 -> term exactly 1, subtracted exactly
//   else                -> mixed: R14 loop verbatim (exact cmp, pads masked)
//   s = r*log2e/sigma clamped +-60; sigmoid = 1/(1+E_i*F_j);
//   1/u+1/v = (u+v)*rcp(u*v); u*v overflows only when both terms ~0: safe.

#define NB 1024
#define BLOCK 256
#define NBLK_DATA 64               // 16384/256
#define RPT 4
#define CHUNK (BLOCK * RPT)        // 1024
#define RC_SHIFT 10
#define MAXRC 16
#define JTILE 64
#define JP_SHIFT 6
#define NPG 256
#define GRID_MAIN 1024

__device__ __forceinline__ float fast_exp2(float x) { return __builtin_amdgcn_exp2f(x); }
__device__ __forceinline__ float fast_rcp(float x)  { return __builtin_amdgcn_rcpf(x); }
__device__ __forceinline__ float clamp60(float x)   { return fminf(fmaxf(x, -60.0f), 60.0f); }
__device__ __forceinline__ int bucket_of(float tv) {
    int b = (int)(tv * (float)NB);
    return min(max(b, 0), NB - 1);
}

// ---- 1) per-block histogram slices (pure overwrite, no memset) --------------
__global__ __launch_bounds__(BLOCK) void k_hist(
    const float* __restrict__ t, const int* __restrict__ ev,
    int* __restrict__ hIb, int* __restrict__ hJb) {
    __shared__ int hI[NB], hJ[NB];
    const int tid = threadIdx.x, b = blockIdx.x;
    for (int i = tid; i < NB; i += BLOCK) { hI[i] = 0; hJ[i] = 0; }
    __syncthreads();
    int g = (b << 8) + tid;
    int bk = bucket_of(t[g]);
    atomicAdd(&hJ[bk], 1);
    if (ev[g] == 1) atomicAdd(&hI[bk], 1);
    __syncthreads();
    int* oI = hIb + b * NB;
    int* oJ = hJb + b * NB;
    for (int i = tid; i < NB; i += BLOCK) { oI[i] = hI[i]; oJ[i] = hJ[i]; }
}

// ---- 2) redundant sum+scan (per block) + bounds + transform/scatter ---------
__global__ __launch_bounds__(BLOCK) void k_scatter(
    const float* __restrict__ r, const float* __restrict__ t,
    const int* __restrict__ ev, float kscale,
    const int* __restrict__ hIb, const int* __restrict__ hJb,
    int* __restrict__ rcLo, int* __restrict__ rcHi,
    int* __restrict__ jpLo, int* __restrict__ jpHi,
    int* __restrict__ nactive_g,
    float2* __restrict__ sI, float2* __restrict__ sJ) {

    const int tid = threadIdx.x, b = blockIdx.x;
    __shared__ int ps[2 * BLOCK];
    __shared__ int baseI[NB], baseJ[NB];
    __shared__ int rcLo_s[MAXRC], rcHi_s[MAXRC], jpLo_s[NPG], jpHi_s[NPG];
    const int bk0 = tid << 2;                 // 4 contiguous buckets per thread

    // column totals over 64 slices + prefix over blocks < b (unroll-8 = MLP)
    int tI[4] = {0,0,0,0}, tJ[4] = {0,0,0,0};
    int pI[4] = {0,0,0,0}, pJ[4] = {0,0,0,0};
#pragma unroll 8
    for (int bb = 0; bb < NBLK_DATA; ++bb) {
        int4 vI = *(const int4*)(hIb + bb * NB + bk0);
        int4 vJ = *(const int4*)(hJb + bb * NB + bk0);
        tI[0] += vI.x; tI[1] += vI.y; tI[2] += vI.z; tI[3] += vI.w;
        tJ[0] += vJ.x; tJ[1] += vJ.y; tJ[2] += vJ.z; tJ[3] += vJ.w;
        int take = (bb < b) ? 1 : 0;
        pI[0] += take * vI.x; pI[1] += take * vI.y; pI[2] += take * vI.z; pI[3] += take * vI.w;
        pJ[0] += take * vJ.x; pJ[1] += take * vJ.y; pJ[2] += take * vJ.z; pJ[3] += take * vJ.w;
    }
    int sIt = (tI[0] + tI[1]) + (tI[2] + tI[3]);
    int sJt = (tJ[0] + tJ[1]) + (tJ[2] + tJ[3]);
    ps[tid] = sIt; ps[BLOCK + tid] = sJt;
    __syncthreads();
    for (int off = 1; off < BLOCK; off <<= 1) {       // dual Hillis-Steele
        int a = (tid >= off) ? ps[tid - off] : 0;
        int c = (tid >= off) ? ps[BLOCK + tid - off] : 0;
        __syncthreads();
        ps[tid] += a; ps[BLOCK + tid] += c;
        __syncthreads();
    }
    int exI = ps[tid] - sIt, exJ = ps[BLOCK + tid] - sJt;
    int eI[4], eJ[4];
    { int runI = exI, runJ = exJ;
#pragma unroll
      for (int k = 0; k < 4; ++k) { eI[k] = runI; runI += tI[k]; eJ[k] = runJ; runJ += tJ[k]; } }

    if (b == 0 && tid == BLOCK - 1) *nactive_g = ps[BLOCK - 1];

    if (b == 0) {   // chunk/page bucket bounds (block-uniform branch)
        if (tid < MAXRC) { rcLo_s[tid] = 0x7fffffff; rcHi_s[tid] = -1; }
        if (tid < NPG)   { jpLo_s[tid] = 0x7fffffff; jpHi_s[tid] = -1; }
        __syncthreads();
#pragma unroll
        for (int k = 0; k < 4; ++k) {
            int bk = bk0 + k;
            if (tI[k] > 0) {
                int c0 = eI[k] >> RC_SHIFT, c1 = (eI[k] + tI[k] - 1) >> RC_SHIFT;
                for (int c = c0; c <= c1; ++c) { atomicMin(&rcLo_s[c], bk); atomicMax(&rcHi_s[c], bk); }
            }
            if (tJ[k] > 0) {
                int c0 = eJ[k] >> JP_SHIFT, c1 = (eJ[k] + tJ[k] - 1) >> JP_SHIFT;
                for (int c = c0; c <= c1; ++c) { atomicMin(&jpLo_s[c], bk); atomicMax(&jpHi_s[c], bk); }
            }
        }
        __syncthreads();
        if (tid < MAXRC) { rcLo[tid] = rcLo_s[tid]; rcHi[tid] = rcHi_s[tid]; }
        if (tid < NPG)   { jpLo[tid] = jpLo_s[tid]; jpHi[tid] = jpHi_s[tid]; }
    }

    // per-bucket cursors for THIS block = global excl + prefix of earlier blocks
#pragma unroll
    for (int k = 0; k < 4; ++k) {
        baseI[bk0 + k] = eI[k] + pI[k];
        baseJ[bk0 + k] = eJ[k] + pJ[k];
    }
    __syncthreads();

    // transform + scatter my element
    int g = (b << 8) + tid;
    float tv = t[g];
    float s  = clamp60(r[g] * kscale);
    int bk = bucket_of(tv);
    int pj = atomicAdd(&baseJ[bk], 1);
    sJ[pj] = make_float2(fast_exp2(-s), tv);       // F_j = 2^{-s_j}
    if (ev[g] == 1) {
        int pi = atomicAdd(&baseI[bk], 1);
        sI[pi] = make_float2(fast_exp2(s), tv);    // E_i = 2^{s_i}
    }
}

// ---- 3) main: balanced classified tiles (cg-major order) --------------------
__global__ __launch_bounds__(BLOCK) void k_main(
    const float2* __restrict__ sI, const float2* __restrict__ sJ,
    const int* __restrict__ rcLo, const int* __restrict__ rcHi,
    const int* __restrict__ jpLo, const int* __restrict__ jpHi,
    const int* __restrict__ nactive_g,
    float* __restrict__ pL, unsigned int* __restrict__ pC) {

    const int tid = threadIdx.x;
    const int nactive = *nactive_g;
    const int nrc = (nactive + CHUNK - 1) / CHUNK;   // ~8
    const int ntiles = nrc * NPG;                     // ~2048

    __shared__ float2 tile[JTILE];

    float lsum = 0.0f;
    int   csum = 0;

    for (int tix = blockIdx.x; tix < ntiles; tix += gridDim.x) {
        // cg-MAJOR: consecutive tix share rc; strided tiles differ in cg by
        // gridDim/nrc pages -> anti-correlated classes per block
        int cg = tix / nrc;
        int rc = tix - cg * nrc;
        int rl = rcLo[rc], rh = rcHi[rc];
        int jh = jpHi[cg];
        if (jh < rl) continue;        // all-false or empty chunk (uniform)
        int jl = jpLo[cg];

        // 4 rows/thread; pads: E=0 (u = 1 exactly), T=3 (mask off)
        float E[RPT], T[RPT];
        int nv = 0;
        int rbase = rc * CHUNK;
#pragma unroll
        for (int k = 0; k < RPT; ++k) {
            int rr = rbase + tid + (k << 8);
            if (rr < nactive) { float2 f = sI[rr]; E[k] = f.x; T[k] = f.y; ++nv; }
            else              { E[k] = 0.0f; T[k] = 3.0f; }
        }

        __syncthreads();
        if (tid < JTILE) tile[tid] = sJ[(cg << 6) + tid];
        __syncthreads();

        if (jl > rh) {
            // ALL-TRUE: no cmp/cndmask/count
            float l0 = 0.f, l1 = 0.f;
#pragma unroll 4
            for (int jj = 0; jj < JTILE; ++jj) {
                float F = tile[jj].x;
                float u0 = __builtin_fmaf(E[0], F, 1.0f);
                float v0 = __builtin_fmaf(E[1], F, 1.0f);
                l0 = __builtin_fmaf(u0 + v0, fast_rcp(u0 * v0), l0);
                float u1 = __builtin_fmaf(E[2], F, 1.0f);
                float v1 = __builtin_fmaf(E[3], F, 1.0f);
                l1 = __builtin_fmaf(u1 + v1, fast_rcp(u1 * v1), l1);
            }
            lsum += (l0 + l1) - (float)((RPT - nv) << 6);  // exact pad removal
            csum += nv << 6;                                // analytic count
        } else {
            // MIXED: exact per-pair compare (R14 loop)
            float l0 = 0.f, l1 = 0.f;
            int c0i = 0, c1i = 0;
#pragma unroll 4
            for (int jj = 0; jj < JTILE; ++jj) {
                float2 q = tile[jj];
                float F = q.x, tj = q.y;
                float u0 = __builtin_fmaf(E[0], F, 1.0f);
                float v0 = __builtin_fmaf(E[1], F, 1.0f);
                float rp0 = fast_rcp(u0 * v0);
                bool m0 = T[0] < tj, m1 = T[1] < tj;
                float num0 = (m0 ? v0 : 0.0f) + (m1 ? u0 : 0.0f);
                l0 = __builtin_fmaf(num0, rp0, l0);
                c0i += m0 + m1;
                float u1 = __builtin_fmaf(E[2], F, 1.0f);
                float v1 = __builtin_fmaf(E[3], F, 1.0f);
                float rp1 = fast_rcp(u1 * v1);
                bool m2 = T[2] < tj, m3 = T[3] < tj;
                float num1 = (m2 ? v1 : 0.0f) + (m3 ? u1 : 0.0f);
                l1 = __builtin_fmaf(num1, rp1, l1);
                c1i += m2 + m3;
            }
            lsum += l0 + l1;
            csum += c0i + c1i;
        }
    }

    // block reduce + plain partial stores
#pragma unroll
    for (int off = 32; off > 0; off >>= 1) {
        lsum += __shfl_down(lsum, off);
        csum += __shfl_down(csum, off);
    }
    __shared__ float lw[BLOCK / 64];
    __shared__ int   cw[BLOCK / 64];
    int wid = tid >> 6;
    if ((tid & 63) == 0) { lw[wid] = lsum; cw[wid] = csum; }
    __syncthreads();
    if (tid == 0) {
        pL[blockIdx.x] = (lw[0] + lw[1]) + (lw[2] + lw[3]);
        pC[blockIdx.x] = (unsigned)((cw[0] + cw[1]) + (cw[2] + cw[3]));
    }
}

// ---- 4) finalize -------------------------------------------------------------
__global__ __launch_bounds__(BLOCK) void k_finalize(
    const float* __restrict__ pL, const unsigned int* __restrict__ pC,
    int n, float* __restrict__ out) {
    double l = 0.0, c = 0.0;
    for (int i = threadIdx.x; i < n; i += BLOCK) {
        l += (double)pL[i];
        c += (double)pC[i];
    }
#pragma unroll
    for (int off = 32; off > 0; off >>= 1) {
        l += __shfl_down(l, off);
        c += __shfl_down(c, off);
    }
    __shared__ double lw[BLOCK / 64], cw[BLOCK / 64];
    int wid = threadIdx.x >> 6;
    if ((threadIdx.x & 63) == 0) { lw[wid] = l; cw[wid] = c; }
    __syncthreads();
    if (threadIdx.x == 0) {
        double L = (lw[0] + lw[1]) + (lw[2] + lw[3]);
        double C = (cw[0] + cw[1]) + (cw[2] + cw[3]);
        out[0] = (float)(L / (C + 1e-6));
    }
}

extern "C" void kernel_launch(void* const* d_in, const int* in_sizes, int n_in,
                              void* d_out, int out_size, void* d_ws, size_t ws_size,
                              hipStream_t stream) {
    const float* r  = (const float*)d_in[0];
    const float* t  = (const float*)d_in[1];
    const int*   ev = (const int*)d_in[2];
    float* out = (float*)d_out;
    const int B = in_sizes[0];   // 16384

    const float SIGMA = 0.1f;
    const float LOG2E = 1.4426950408889634f;
    const float kscale = LOG2E / SIGMA;

    char* ws = (char*)d_ws;
    int* rcLo = (int*)(ws + 0);
    int* rcHi = (int*)(ws + 256);
    int* jpLo = (int*)(ws + 512);
    int* jpHi = (int*)(ws + 1536);
    int* nactive_g = (int*)(ws + 2560);
    int* hIb   = (int*)(ws + 4096);                       // 64*1024*4 = 256 KB
    int* hJb   = (int*)(ws + 4096 + 262144);              // 256 KB
    float2* sI = (float2*)(ws + 4096 + 524288);           // 128 KB
    float2* sJ = (float2*)(ws + 4096 + 524288 + 131072);  // 128 KB
    float*  pL = (float*)(ws + 4096 + 524288 + 262144);
    unsigned int* pC = (unsigned int*)((char*)pL + (size_t)GRID_MAIN * 4);

    k_hist<<<NBLK_DATA, BLOCK, 0, stream>>>(t, ev, hIb, hJb);
    k_scatter<<<NBLK_DATA, BLOCK, 0, stream>>>(r, t, ev, kscale, hIb, hJb,
        rcLo, rcHi, jpLo, jpHi, nactive_g, sI, sJ);
    k_main<<<GRID_MAIN, BLOCK, 0, stream>>>(sI, sJ, rcLo, rcHi, jpLo, jpHi,
        nactive_g, pL, pC);
    k_finalize<<<1, BLOCK, 0, stream>>>(pL, pC, GRID_MAIN, out);
}

// Round 18
// 38.586 us; speedup vs baseline: 1.4677x; 1.4677x over previous
//
#include <hip/hip_runtime.h>

// DifferentiableCIndexLoss:
//   mask[i,j] = (t[i] < t[j]) && (e[i]==1)
//   loss = sum sigmoid((r[j]-r[i])/SIGMA) * mask ;  count = sum mask
//   out  = loss / (count + 1e-6)
//
// R18 = R14 (best, 40.6us) with the memset node ELIMINATED (4 -> 3 nodes).
// k_compact is now deterministic and atomic-free: block b's exclusive base =
// sum(ev[0 .. b*256)) computed by direct coalesced summation (<=63 loads per
// thread, block-reduce); within-block order via ballot prefix; last block
// writes nactive. No cursor, no memset, no atomics anywhere in the pipeline.
// Sorted-classification family retired for good (R4-R9,R16,R17: prep +
// imbalance always exceeded the ~13us it saved in main).
// k_main: R14 verbatim -- pre-transformed sI=(2^s,t)/sJ=(2^-s,t), RPT=8,
// JTILE=64, grid 1024 grid-stride, paired-rcp, 4 independent fp+int chains,
// LDS wave-uniform broadcast, plain partial stores; double-precision finalize.
//   s = r*log2e/sigma clamped +-60: 2^{si-sj} in [2^-120,2^120].

#define BLOCK 256
#define RPT 8                        // rows per thread
#define ROWS_PER_TILE (BLOCK * RPT)  // 2048
#define JTILE 64                     // cols per tile
#define NCOLGRP 256                  // 16384/64
#define GRID_MAIN 1024               // = nrc(4) * 256

__device__ __forceinline__ float fast_exp2(float x) { return __builtin_amdgcn_exp2f(x); }
__device__ __forceinline__ float fast_rcp(float x)  { return __builtin_amdgcn_rcpf(x); }
__device__ __forceinline__ float clamp60(float x)   { return fminf(fmaxf(x, -60.0f), 60.0f); }

// ---- 1) transform cols + compact active rows (deterministic, no atomics) ----
__global__ __launch_bounds__(BLOCK) void k_compact(
    const float* __restrict__ r, const float* __restrict__ t,
    const int* __restrict__ ev, int B, float kscale,
    int* __restrict__ nactive_g,
    float2* __restrict__ sI, float2* __restrict__ sJ) {
    const int tid = threadIdx.x, b = blockIdx.x;
    const int lane = tid & 63, wid = tid >> 6;
    int g = (b << 8) + tid;

    float tv = t[g];
    float s  = clamp60(r[g] * kscale);
    sJ[g] = make_float2(fast_exp2(-s), tv);        // F_j = 2^{-s_j}

    // exclusive base for this block: #active in [0, b*256), direct summation
    int pre = 0;
    const int lim = b << 8;
    for (int k = tid; k < lim; k += BLOCK) pre += ev[k];   // coalesced, MLP
#pragma unroll
    for (int off = 32; off > 0; off >>= 1) pre += __shfl_down(pre, off);
    __shared__ int wsum[BLOCK / 64];
    if (lane == 0) wsum[wid] = pre;
    __syncthreads();
    const int base = (wsum[0] + wsum[1]) + (wsum[2] + wsum[3]);

    // within-block compaction order via ballot prefix
    bool pred = (ev[g] == 1);
    unsigned long long bal = __ballot(pred);
    int before = __popcll(bal & ((1ull << lane) - 1ull));
    int wcnt = __popcll(bal);
    __shared__ int woff[BLOCK / 64];
    if (lane == 0) woff[wid] = wcnt;
    __syncthreads();
    int wbase = 0;
#pragma unroll
    for (int w = 0; w < BLOCK / 64; ++w) wbase += (w < wid) ? woff[w] : 0;
    if (pred) sI[base + wbase + before] = make_float2(fast_exp2(s), tv);

    if (b == gridDim.x - 1 && tid == 0)
        *nactive_g = base + ((woff[0] + woff[1]) + (woff[2] + woff[3]));
}

// ---- 2) main: all-pairs, RPT=8, independent accumulator chains (R14) --------
__global__ __launch_bounds__(BLOCK) void k_main(
    const float2* __restrict__ sI, const float2* __restrict__ sJ,
    const int* __restrict__ nactive_g,
    float* __restrict__ pL, unsigned int* __restrict__ pC) {

    const int tid = threadIdx.x;
    const int nactive = *nactive_g;
    const int nrc = (nactive + ROWS_PER_TILE - 1) / ROWS_PER_TILE;  // ~4
    const int ntiles = nrc * NCOLGRP;                                // ~1024

    __shared__ float2 tile[JTILE];

    float lsum = 0.0f;
    int   csum = 0;

    for (int tix = blockIdx.x; tix < ntiles; tix += gridDim.x) {
        int rc = tix >> 8;            // row chunk (ntiles = nrc*256)
        int cg = tix & (NCOLGRP - 1); // col group

        float E[RPT], T[RPT];
        int rbase = rc * ROWS_PER_TILE;
#pragma unroll
        for (int k = 0; k < RPT; ++k) {
            int rr = rbase + tid + (k << 8);
            if (rr < nactive) { float2 f = sI[rr]; E[k] = f.x; T[k] = f.y; }
            else              { E[k] = 1.0f; T[k] = 3.0f; }
            // pad: FINITE E (mask kills num & count); NOT inf (shared product!)
        }

        __syncthreads();              // protect tile[] from previous iteration
        if (tid < JTILE) tile[tid] = sJ[(cg << 6) + tid];
        __syncthreads();

        float l[4] = {0.f, 0.f, 0.f, 0.f};
        int   c[4] = {0, 0, 0, 0};
#pragma unroll 4
        for (int jj = 0; jj < JTILE; ++jj) {
            float2 q = tile[jj];      // wave-uniform LDS broadcast
            float F = q.x, tj = q.y;
#pragma unroll
            for (int g2 = 0; g2 < 4; ++g2) {      // 4 independent pair-groups
                float u = __builtin_fmaf(E[2*g2],   F, 1.0f);
                float v = __builtin_fmaf(E[2*g2+1], F, 1.0f);
                float p = fminf(u * v, 3.0e38f);
                float rp = fast_rcp(p);
                bool m0 = T[2*g2]   < tj;
                bool m1 = T[2*g2+1] < tj;
                float num = (m0 ? v : 0.0f) + (m1 ? u : 0.0f);
                l[g2] = __builtin_fmaf(num, rp, l[g2]);   // own fp chain
                c[g2] += m0 + m1;                          // own int chain
            }
        }
        lsum += (l[0] + l[1]) + (l[2] + l[3]);
        csum += (c[0] + c[1]) + (c[2] + c[3]);
    }

    // block reduce + plain partial stores
#pragma unroll
    for (int off = 32; off > 0; off >>= 1) {
        lsum += __shfl_down(lsum, off);
        csum += __shfl_down(csum, off);
    }
    __shared__ float lw[BLOCK / 64];
    __shared__ int   cw[BLOCK / 64];
    int wid = tid >> 6;
    if ((tid & 63) == 0) { lw[wid] = lsum; cw[wid] = csum; }
    __syncthreads();
    if (tid == 0) {
        pL[blockIdx.x] = (lw[0] + lw[1]) + (lw[2] + lw[3]);
        pC[blockIdx.x] = (unsigned)((cw[0] + cw[1]) + (cw[2] + cw[3]));
    }
}

// ---- 3) finalize -------------------------------------------------------------
__global__ __launch_bounds__(BLOCK) void k_finalize(
    const float* __restrict__ pL, const unsigned int* __restrict__ pC,
    int n, float* __restrict__ out) {
    double l = 0.0, c = 0.0;
    for (int i = threadIdx.x; i < n; i += BLOCK) {
        l += (double)pL[i];
        c += (double)pC[i];
    }
#pragma unroll
    for (int off = 32; off > 0; off >>= 1) {
        l += __shfl_down(l, off);
        c += __shfl_down(c, off);
    }
    __shared__ double lw[BLOCK / 64], cw[BLOCK / 64];
    int wid = threadIdx.x >> 6;
    if ((threadIdx.x & 63) == 0) { lw[wid] = l; cw[wid] = c; }
    __syncthreads();
    if (threadIdx.x == 0) {
        double L = (lw[0] + lw[1]) + (lw[2] + lw[3]);
        double C = (cw[0] + cw[1]) + (cw[2] + cw[3]);
        out[0] = (float)(L / (C + 1e-6));
    }
}

extern "C" void kernel_launch(void* const* d_in, const int* in_sizes, int n_in,
                              void* d_out, int out_size, void* d_ws, size_t ws_size,
                              hipStream_t stream) {
    const float* r  = (const float*)d_in[0];
    const float* t  = (const float*)d_in[1];
    const int*   ev = (const int*)d_in[2];
    float* out = (float*)d_out;
    const int B = in_sizes[0];   // 16384

    const float SIGMA = 0.1f;
    const float LOG2E = 1.4426950408889634f;
    const float kscale = LOG2E / SIGMA;

    char* ws = (char*)d_ws;
    int* nactive_g = (int*)ws;                     // written by k_compact
    float2* sI  = (float2*)(ws + 4096);            // 128 KB (compacted rows: E, t)
    float2* sJ  = sI + B;                          // 128 KB (all cols: F, t)
    float*  pL  = (float*)(sJ + B);
    unsigned int* pC = (unsigned int*)(pL + GRID_MAIN);

    const int nblk = (B + BLOCK - 1) / BLOCK;      // 64

    k_compact<<<nblk, BLOCK, 0, stream>>>(r, t, ev, B, kscale, nactive_g, sI, sJ);
    k_main<<<GRID_MAIN, BLOCK, 0, stream>>>(sI, sJ, nactive_g, pL, pC);
    k_finalize<<<1, BLOCK, 0, stream>>>(pL, pC, GRID_MAIN, out);
}